// Round 18
// baseline (439.443 us; speedup 1.0000x reference)
//
#include <hip/hip_runtime.h>
#include <math.h>

// Problem constants: B=8, Cin=64, Cout=128, H=W=128, KS=3, N=9, K=576
#define KDIM 576
#define AHSTRIDE 584   // f16 per position row (576 + 8 pad), 1168 B = 73 uint4, 16B-aligned

typedef _Float16 h2 __attribute__((ext_vector_type(2)));

__device__ inline float dot8(uint4 a, uint4 w, float acc) {
    acc = __builtin_amdgcn_fdot2(__builtin_bit_cast(h2, a.x), __builtin_bit_cast(h2, w.x), acc, false);
    acc = __builtin_amdgcn_fdot2(__builtin_bit_cast(h2, a.y), __builtin_bit_cast(h2, w.y), acc, false);
    acc = __builtin_amdgcn_fdot2(__builtin_bit_cast(h2, a.z), __builtin_bit_cast(h2, w.z), acc, false);
    acc = __builtin_amdgcn_fdot2(__builtin_bit_cast(h2, a.w), __builtin_bit_cast(h2, w.w), acc, false);
    return acc;
}

// ---------------- zero only the padding border of x_t ----------------
// border cells per b: rows 0,129 (130 each) + cols 0,129 of rows 1..128 (128 each) = 516
__global__ void k_zero_border(float4* __restrict__ xt4) {
    int i = blockIdx.x * 256 + threadIdx.x;        // total 8*516*16 = 66048 float4
    if (i >= 66048) return;
    int f4 = i & 15, cell = (i >> 4) % 516, b = i / (516 * 16);
    int r, c;
    if (cell < 130)      { r = 0;              c = cell; }
    else if (cell < 260) { r = 129;            c = cell - 130; }
    else if (cell < 388) { r = cell - 260 + 1; c = 0; }
    else                 { r = cell - 388 + 1; c = 129; }
    xt4[(((size_t)b * 130 + r) * 130 + c) * 16 + f4] = make_float4(0.f, 0.f, 0.f, 0.f);
}

// ---------------- pad + NCHW->NHWC transpose ----------------
__global__ __launch_bounds__(256) void k_pad_transpose(
    const float* __restrict__ x, float* __restrict__ x_t) {
    __shared__ float lds[128 * 65];
    int b = blockIdx.x >> 7;
    int h = blockIdx.x & 127;
    for (int e = threadIdx.x; e < 64 * 128; e += 256) {
        int ci = e >> 7, w = e & 127;
        lds[w * 65 + ci] = x[((b * 64 + ci) * 128 + h) * 128 + w];
    }
    __syncthreads();
    for (int e = threadIdx.x; e < 128 * 64; e += 256) {
        int w = e >> 6, ci = e & 63;
        x_t[((b * 130 + h + 1) * 130 + (w + 1)) * 64 + ci] = lds[w * 65 + ci];
    }
}

// ---------------- combined weight prepack: Wc -> Wh (k8-blocked), Wp/Wm -> Wh27 ----------------
__global__ void k_wcomb(const float* __restrict__ Wc, const float* __restrict__ Wp,
                        const float* __restrict__ Wm, _Float16* __restrict__ Wh,
                        _Float16* __restrict__ Wh27) {
    int gb = blockIdx.x;
    if (gb < 288) {
        int e = gb * 256 + threadIdx.x;
        if (e >= 72 * 128 * 8) return;
        int j = e & 7, idx = e >> 3;
        int co = idx & 127, k8 = idx >> 7;
        int kp = k8 * 8 + j;
        int n = kp >> 6, ci = kp & 63;
        Wh[e] = (_Float16)Wc[co * KDIM + ci * 9 + n];
    } else {
        int e = (gb - 288) * 256 + threadIdx.x;
        if (e >= 73 * 32 * 8) return;
        int j = e & 7, idx = e >> 3;
        int co = idx & 31, k8 = idx >> 5;
        float v = 0.f;
        if (k8 < 72 && co < 27) {
            int kp = k8 * 8 + j;
            int n = kp >> 6, ci = kp & 63;
            v = (co < 18) ? Wp[co * KDIM + ci * 9 + n] : Wm[(co - 18) * KDIM + ci * 9 + n];
        }
        Wh27[e] = (_Float16)v;
    }
}

// ---------------- offset + mask convs: f16 fdot2 (R17-proven) ----------------
__global__ __launch_bounds__(256) void k_offmask(
    const float* __restrict__ x_t, const _Float16* __restrict__ Wh27,
    const float* __restrict__ bp, const float* __restrict__ bm,
    float* __restrict__ offs, float* __restrict__ mask) {
    __shared__ __align__(16) _Float16 a_lds[32 * AHSTRIDE];   // 37376 B

    int blk = blockIdx.x;
    int b  = blk & 7;
    int rem = blk >> 3;
    int h  = rem >> 2;
    int w0 = (rem & 3) * 32;
    int tid = threadIdx.x;

    {
        const float* xb = x_t + (size_t)b * 130 * 130 * 64;
        int ci = tid & 63;
        for (int it = 0; it < 72; ++it) {
            int point = (tid >> 6) + it * 4;            // pos*9 + n, point < 288
            int pos = (point * 456) >> 12;
            int n = point - pos * 9;
            int kx = n / 3, ky = n - kx * 3;
            float v = xb[((h + kx) * 130 + (w0 + pos + ky)) * 64 + ci];
            a_lds[pos * AHSTRIDE + n * 64 + ci] = (_Float16)v;
        }
    }
    __syncthreads();

    int co = tid & 31;
    int ph = (tid >> 5) & 1;
    int wv = tid >> 6;
    int pbase = wv * 8 + ph * 4;
    const uint4* W4 = (const uint4*)Wh27;
    float acc[4] = {0.f, 0.f, 0.f, 0.f};
    uint4 wc = W4[co];
    for (int k8 = 0; k8 < 72; ++k8) {
        uint4 wn = W4[(k8 + 1) * 32 + co];              // k8=71 reads zero pad row
        #pragma unroll
        for (int p = 0; p < 4; ++p) {
            uint4 a = *(const uint4*)&a_lds[(pbase + p) * AHSTRIDE + k8 * 8];
            acc[p] = dot8(a, wc, acc[p]);
        }
        wc = wn;
    }

    if (co < 27) {
        #pragma unroll
        for (int p = 0; p < 4; ++p) {
            int w = w0 + pbase + p;
            int idx = ((b * 128 + h) * 128 + w);
            if (co < 18) {
                offs[idx * 18 + co] = acc[p] + bp[co];
            } else {
                float v = acc[p] + bm[co - 18];
                mask[idx * 9 + (co - 18)] = 1.f / (1.f + __expf(-v));
            }
        }
    }
}

// ---------------- main: deformable sample -> f16 fdot2, half-wave pos split ----------------
// block = 16 positions; grid = 8192, XCD-pinned; LDS 22.7 KB -> 7 blocks/CU.
// Phase 3: wave wv covers pos [wv*4, wv*4+4); half-wave hp picks a pos PAIR, so each
// ds_read_b128 serves 2 positions (2 addrs/wave = free 2-way). Thread = 4 co x 2 pos.
__global__ __launch_bounds__(256, 6) void k_main(
    const float* __restrict__ x_t, const float* __restrict__ offs,
    const float* __restrict__ mask, const _Float16* __restrict__ Wh,
    float* __restrict__ out) {
    __shared__ __align__(16) _Float16 a_lds[16 * AHSTRIDE];   // 18688 B; reused as outst
    __shared__ int    pi3[144 * 3];                           // lt, rb, dy
    __shared__ float4 pg4[144];

    int blk = blockIdx.x;
    int b  = blk & 7;                  // XCD swizzle: one batch per XCD
    int rem = blk >> 3;
    int h  = rem >> 3;
    int w0 = (rem & 7) * 16;
    int tid = threadIdx.x;

    // phase 1: sampling coords for 16 pos x 9 pts (proven math)
    if (tid < 144) {
        int e = tid;
        int pos = e / 9, n = e - pos * 9;
        int w = w0 + pos;
        int idx = ((b * 128 + h) * 128 + w);
        float ox = offs[idx * 18 + n];
        float oy = offs[idx * 18 + 9 + n];
        float mv = mask[idx * 9 + n];
        float px = ox + (float)(h + n / 3);
        float py = oy + (float)(w + n % 3);
        float flx = floorf(px), fly = floorf(py);
        float qltx = fminf(fmaxf(flx, 0.f), 129.f);
        float qlty = fminf(fmaxf(fly, 0.f), 129.f);
        float qrbx = fminf(fmaxf(flx + 1.f, 0.f), 129.f);
        float qrby = fminf(fmaxf(fly + 1.f, 0.f), 129.f);
        float pxc = fminf(fmaxf(px, 0.f), 129.f);
        float pyc = fminf(fmaxf(py, 0.f), 129.f);
        float glt = (1.f + qltx - pxc) * (1.f + qlty - pyc);
        float grb = (1.f - qrbx + pxc) * (1.f - qrby + pyc);
        float glb = (1.f + qltx - pxc) * (1.f - qrby + pyc);
        float grt = (1.f - qrbx + pxc) * (1.f + qlty - pyc);
        int ix_lt = (int)qltx, iy_lt = (int)qlty, ix_rb = (int)qrbx, iy_rb = (int)qrby;
        pi3[e * 3 + 0] = (ix_lt * 130 + iy_lt) * 64;
        pi3[e * 3 + 1] = (ix_rb * 130 + iy_rb) * 64;
        pi3[e * 3 + 2] = (iy_rb - iy_lt) * 64;
        pg4[e] = make_float4(glt * mv, grb * mv, glb * mv, grt * mv);
    }
    __syncthreads();

    // phase 2: gather+blend, a_lds[pos][k' = n*64 + ci] in f16 (proven pattern)
    {
        const float* xb = x_t + (size_t)b * 130 * 130 * 64;
        int ci = tid & 63;
        for (int it = 0; it < 36; ++it) {
            int point = (tid >> 6) + it * 4;
            int pos = (point * 456) >> 12;          // point/9, exact for point<288
            int n = point - pos * 9;
            int lt = pi3[point * 3 + 0];
            int rb = pi3[point * 3 + 1];
            int dy = pi3[point * 3 + 2];
            float4 g = pg4[point];
            float v = g.x * xb[lt + ci] + g.y * xb[rb + ci] +
                      g.z * xb[lt + dy + ci] + g.w * xb[rb - dy + ci];
            a_lds[pos * AHSTRIDE + n * 64 + ci] = (_Float16)v;
        }
    }
    __syncthreads();

    // phase 3: fdot2 dot, half-wave pos split. cl = co base lane, hp = pos pair.
    int lane = tid & 63, wv = tid >> 6;
    int cl = lane & 31, hp = lane >> 5;
    int pbase = wv * 4 + hp * 2;
    const uint4* A4 = (const uint4*)a_lds;           // row stride 73 uint4
    const uint4* W4 = (const uint4*)Wh;              // [(k8*128 + co)] = 8 f16
    float acc[4][2] = {{0.f,0.f},{0.f,0.f},{0.f,0.f},{0.f,0.f}};
    int arow0 = pbase * 73, arow1 = arow0 + 73;

    uint4 wc0 = W4[cl], wc1 = W4[cl + 32], wc2 = W4[cl + 64], wc3 = W4[cl + 96];
    #pragma unroll 2
    for (int k8 = 0; k8 < 72; ++k8) {
        // prefetch next k8 (k8=71 over-reads into Wh27 slot: benign, discarded)
        uint4 wn0 = W4[(k8 + 1) * 128 + cl];
        uint4 wn1 = W4[(k8 + 1) * 128 + cl + 32];
        uint4 wn2 = W4[(k8 + 1) * 128 + cl + 64];
        uint4 wn3 = W4[(k8 + 1) * 128 + cl + 96];
        uint4 a0 = A4[arow0 + k8];                   // 2 addrs per wave: free 2-way
        uint4 a1 = A4[arow1 + k8];
        acc[0][0] = dot8(a0, wc0, acc[0][0]);
        acc[0][1] = dot8(a1, wc0, acc[0][1]);
        acc[1][0] = dot8(a0, wc1, acc[1][0]);
        acc[1][1] = dot8(a1, wc1, acc[1][1]);
        acc[2][0] = dot8(a0, wc2, acc[2][0]);
        acc[2][1] = dot8(a1, wc2, acc[2][1]);
        acc[3][0] = dot8(a0, wc3, acc[3][0]);
        acc[3][1] = dot8(a1, wc3, acc[3][1]);
        wc0 = wn0; wc1 = wn1; wc2 = wn2; wc3 = wn3;
    }
    __syncthreads();   // all a_lds reads done before aliasing overwrite

    // epilogue: stage via LDS, then coalesced global stores (proven path)
    float* outst = (float*)a_lds;                    // [128 co][17]
    #pragma unroll
    for (int c = 0; c < 4; ++c)
        #pragma unroll
        for (int p = 0; p < 2; ++p)
            outst[(cl + 32 * c) * 17 + pbase + p] = acc[c][p];
    __syncthreads();
    for (int e = tid; e < 2048; e += 256) {
        int co2 = e >> 4, wl = e & 15;
        out[((size_t)(b * 128 + co2) * 16384) + h * 128 + w0 + wl] = outst[co2 * 17 + wl];
    }
}

// ---------------- BN stats: one block per (b, co) ----------------
__global__ __launch_bounds__(256) void k_stats(
    const float* __restrict__ out, float* __restrict__ partial) {
    __shared__ float s1[256], s2[256];
    int blk = blockIdx.x;
    const float4* p = (const float4*)(out + (size_t)blk * 16384);
    float a1 = 0.f, a2 = 0.f;
    for (int i = threadIdx.x; i < 4096; i += 256) {
        float4 v = p[i];
        a1 += v.x + v.y + v.z + v.w;
        a2 += v.x * v.x + v.y * v.y + v.z * v.z + v.w * v.w;
    }
    s1[threadIdx.x] = a1; s2[threadIdx.x] = a2;
    __syncthreads();
    for (int s = 128; s > 0; s >>= 1) {
        if (threadIdx.x < (unsigned)s) {
            s1[threadIdx.x] += s1[threadIdx.x + s];
            s2[threadIdx.x] += s2[threadIdx.x + s];
        }
        __syncthreads();
    }
    if (threadIdx.x == 0) { partial[blk] = s1[0]; partial[1024 + blk] = s2[0]; }
}

// ---------------- fused finalize + BN + ReLU ----------------
// block covers exactly one channel c (4096 consecutive floats); stats via 16 scalar loads
__global__ void k_bnrelu(float* __restrict__ out, const float* __restrict__ partial,
                         const float* __restrict__ gamma, const float* __restrict__ beta) {
    int i = blockIdx.x * 256 + threadIdx.x;        // float4 index
    int c = (i >> 12) & 127;
    float s1 = 0.f, s2 = 0.f;
    #pragma unroll
    for (int b = 0; b < 8; ++b) {
        s1 += partial[b * 128 + c];
        s2 += partial[1024 + b * 128 + c];
    }
    const float M = 131072.f;
    float mean = s1 / M;
    float var = fmaxf(s2 / M - mean * mean, 0.f);
    float sc = gamma[c] * rsqrtf(var + 1e-5f);
    float bi = beta[c] - mean * sc;
    float4 v = ((float4*)out)[i];
    v.x = fmaxf(v.x * sc + bi, 0.f);
    v.y = fmaxf(v.y * sc + bi, 0.f);
    v.z = fmaxf(v.z * sc + bi, 0.f);
    v.w = fmaxf(v.w * sc + bi, 0.f);
    ((float4*)out)[i] = v;
}

extern "C" void kernel_launch(void* const* d_in, const int* in_sizes, int n_in,
                              void* d_out, int out_size, void* d_ws, size_t ws_size,
                              hipStream_t stream) {
    const float* x     = (const float*)d_in[0];
    const float* Wp    = (const float*)d_in[1];
    const float* bp    = (const float*)d_in[2];
    const float* Wm    = (const float*)d_in[3];
    const float* bm    = (const float*)d_in[4];
    const float* Wc    = (const float*)d_in[5];
    const float* gamma = (const float*)d_in[6];
    const float* beta  = (const float*)d_in[7];
    float* out = (float*)d_out;
    float* ws  = (float*)d_ws;

    // ws layout (floats)
    float* x_t      = ws;                                   // 8,652,800
    _Float16* Wh    = (_Float16*)(x_t + 8652800);           // 73,728 f16 (36,864 f)
    _Float16* Wh27  = (_Float16*)(x_t + 8652800 + 36864);   // 18,688 f16 (slot 36,864 f)
    float* offs     = x_t + 8652800 + 73728;                // 2,359,296
    float* mask     = offs + 2359296;                       // 1,179,648
    float* partial  = mask + 1179648;                       // 2048

    k_zero_border<<<258, 256, 0, stream>>>((float4*)x_t);
    k_pad_transpose<<<1024, 256, 0, stream>>>(x, x_t);
    k_wcomb<<<361, 256, 0, stream>>>(Wc, Wp, Wm, Wh, Wh27);
    k_offmask<<<4096, 256, 0, stream>>>(x_t, Wh27, bp, bm, offs, mask);
    k_main<<<8192, 256, 0, stream>>>(x_t, offs, mask, Wh, out);
    k_stats<<<1024, 256, 0, stream>>>(out, partial);
    k_bnrelu<<<16384, 256, 0, stream>>>(out, partial, gamma, beta);
}

// Round 19
// 363.596 us; speedup vs baseline: 1.2086x; 1.2086x over previous
//
#include <hip/hip_runtime.h>
#include <math.h>

// Problem constants: B=8, Cin=64, Cout=128, H=W=128, KS=3, N=9, K=576
#define KDIM 576
#define AHSTRIDE 584   // f16 per position row (576 + 8 pad), 1168 B = 73 uint4, 16B-aligned

typedef _Float16 h2 __attribute__((ext_vector_type(2)));

__device__ inline float dot8(uint4 a, uint4 w, float acc) {
    acc = __builtin_amdgcn_fdot2(__builtin_bit_cast(h2, a.x), __builtin_bit_cast(h2, w.x), acc, false);
    acc = __builtin_amdgcn_fdot2(__builtin_bit_cast(h2, a.y), __builtin_bit_cast(h2, w.y), acc, false);
    acc = __builtin_amdgcn_fdot2(__builtin_bit_cast(h2, a.z), __builtin_bit_cast(h2, w.z), acc, false);
    acc = __builtin_amdgcn_fdot2(__builtin_bit_cast(h2, a.w), __builtin_bit_cast(h2, w.w), acc, false);
    return acc;
}

// ---------------- zero only the padding border of x_t ----------------
__global__ void k_zero_border(float4* __restrict__ xt4) {
    int i = blockIdx.x * 256 + threadIdx.x;        // total 8*516*16 = 66048 float4
    if (i >= 66048) return;
    int f4 = i & 15, cell = (i >> 4) % 516, b = i / (516 * 16);
    int r, c;
    if (cell < 130)      { r = 0;              c = cell; }
    else if (cell < 260) { r = 129;            c = cell - 130; }
    else if (cell < 388) { r = cell - 260 + 1; c = 0; }
    else                 { r = cell - 388 + 1; c = 129; }
    xt4[(((size_t)b * 130 + r) * 130 + c) * 16 + f4] = make_float4(0.f, 0.f, 0.f, 0.f);
}

// ---------------- pad + NCHW->NHWC transpose ----------------
__global__ __launch_bounds__(256) void k_pad_transpose(
    const float* __restrict__ x, float* __restrict__ x_t) {
    __shared__ float lds[128 * 65];
    int b = blockIdx.x >> 7;
    int h = blockIdx.x & 127;
    for (int e = threadIdx.x; e < 64 * 128; e += 256) {
        int ci = e >> 7, w = e & 127;
        lds[w * 65 + ci] = x[((b * 64 + ci) * 128 + h) * 128 + w];
    }
    __syncthreads();
    for (int e = threadIdx.x; e < 128 * 64; e += 256) {
        int w = e >> 6, ci = e & 63;
        x_t[((b * 130 + h + 1) * 130 + (w + 1)) * 64 + ci] = lds[w * 65 + ci];
    }
}

// ---------------- combined weight prepack: Wc -> Wh (k8-blocked), Wp/Wm -> Wh27 ----------------
__global__ void k_wcomb(const float* __restrict__ Wc, const float* __restrict__ Wp,
                        const float* __restrict__ Wm, _Float16* __restrict__ Wh,
                        _Float16* __restrict__ Wh27) {
    int gb = blockIdx.x;
    if (gb < 288) {
        int e = gb * 256 + threadIdx.x;
        if (e >= 72 * 128 * 8) return;
        int j = e & 7, idx = e >> 3;
        int co = idx & 127, k8 = idx >> 7;
        int kp = k8 * 8 + j;
        int n = kp >> 6, ci = kp & 63;
        Wh[e] = (_Float16)Wc[co * KDIM + ci * 9 + n];
    } else {
        int e = (gb - 288) * 256 + threadIdx.x;
        if (e >= 73 * 32 * 8) return;
        int j = e & 7, idx = e >> 3;
        int co = idx & 31, k8 = idx >> 5;
        float v = 0.f;
        if (k8 < 72 && co < 27) {
            int kp = k8 * 8 + j;
            int n = kp >> 6, ci = kp & 63;
            v = (co < 18) ? Wp[co * KDIM + ci * 9 + n] : Wm[(co - 18) * KDIM + ci * 9 + n];
        }
        Wh27[e] = (_Float16)v;
    }
}

// ---------------- offset + mask convs: f16 fdot2 (R17-proven) ----------------
__global__ __launch_bounds__(256) void k_offmask(
    const float* __restrict__ x_t, const _Float16* __restrict__ Wh27,
    const float* __restrict__ bp, const float* __restrict__ bm,
    float* __restrict__ offs, float* __restrict__ mask) {
    __shared__ __align__(16) _Float16 a_lds[32 * AHSTRIDE];   // 37376 B

    int blk = blockIdx.x;
    int b  = blk & 7;
    int rem = blk >> 3;
    int h  = rem >> 2;
    int w0 = (rem & 3) * 32;
    int tid = threadIdx.x;

    {
        const float* xb = x_t + (size_t)b * 130 * 130 * 64;
        int ci = tid & 63;
        for (int it = 0; it < 72; ++it) {
            int point = (tid >> 6) + it * 4;            // pos*9 + n, point < 288
            int pos = (point * 456) >> 12;
            int n = point - pos * 9;
            int kx = n / 3, ky = n - kx * 3;
            float v = xb[((h + kx) * 130 + (w0 + pos + ky)) * 64 + ci];
            a_lds[pos * AHSTRIDE + n * 64 + ci] = (_Float16)v;
        }
    }
    __syncthreads();

    int co = tid & 31;
    int ph = (tid >> 5) & 1;
    int wv = tid >> 6;
    int pbase = wv * 8 + ph * 4;
    const uint4* W4 = (const uint4*)Wh27;
    float acc[4] = {0.f, 0.f, 0.f, 0.f};
    uint4 wc = W4[co];
    for (int k8 = 0; k8 < 72; ++k8) {
        uint4 wn = W4[(k8 + 1) * 32 + co];              // k8=71 reads zero pad row
        #pragma unroll
        for (int p = 0; p < 4; ++p) {
            uint4 a = *(const uint4*)&a_lds[(pbase + p) * AHSTRIDE + k8 * 8];
            acc[p] = dot8(a, wc, acc[p]);
        }
        wc = wn;
    }

    if (co < 27) {
        #pragma unroll
        for (int p = 0; p < 4; ++p) {
            int w = w0 + pbase + p;
            int idx = ((b * 128 + h) * 128 + w);
            if (co < 18) {
                offs[idx * 18 + co] = acc[p] + bp[co];
            } else {
                float v = acc[p] + bm[co - 18];
                mask[idx * 9 + (co - 18)] = 1.f / (1.f + __expf(-v));
            }
        }
    }
}

// ---------------- main: deformable sample -> f16 fdot2 dot (R16-proven phase 3) ----------------
// block = 16 positions; grid = 8192, XCD-pinned; LDS 22.7 KB.
// Phase 3: wave = pos-group of 4 (wave-uniform broadcast ds_reads), lane = co (+64);
// thread = 2 co x 4 pos; one coalesced uint4 weight pair per k8 with register prefetch.
__global__ __launch_bounds__(256, 6) void k_main(
    const float* __restrict__ x_t, const float* __restrict__ offs,
    const float* __restrict__ mask, const _Float16* __restrict__ Wh,
    float* __restrict__ out) {
    __shared__ __align__(16) _Float16 a_lds[16 * AHSTRIDE];   // 18688 B; reused as outst
    __shared__ int    pi3[144 * 3];                           // lt, rb, dy
    __shared__ float4 pg4[144];

    int blk = blockIdx.x;
    int b  = blk & 7;                  // XCD swizzle: one batch per XCD
    int rem = blk >> 3;
    int h  = rem >> 3;
    int w0 = (rem & 7) * 16;
    int tid = threadIdx.x;

    // phase 1: sampling coords for 16 pos x 9 pts (proven math)
    if (tid < 144) {
        int e = tid;
        int pos = e / 9, n = e - pos * 9;
        int w = w0 + pos;
        int idx = ((b * 128 + h) * 128 + w);
        float ox = offs[idx * 18 + n];
        float oy = offs[idx * 18 + 9 + n];
        float mv = mask[idx * 9 + n];
        float px = ox + (float)(h + n / 3);
        float py = oy + (float)(w + n % 3);
        float flx = floorf(px), fly = floorf(py);
        float qltx = fminf(fmaxf(flx, 0.f), 129.f);
        float qlty = fminf(fmaxf(fly, 0.f), 129.f);
        float qrbx = fminf(fmaxf(flx + 1.f, 0.f), 129.f);
        float qrby = fminf(fmaxf(fly + 1.f, 0.f), 129.f);
        float pxc = fminf(fmaxf(px, 0.f), 129.f);
        float pyc = fminf(fmaxf(py, 0.f), 129.f);
        float glt = (1.f + qltx - pxc) * (1.f + qlty - pyc);
        float grb = (1.f - qrbx + pxc) * (1.f - qrby + pyc);
        float glb = (1.f + qltx - pxc) * (1.f - qrby + pyc);
        float grt = (1.f - qrbx + pxc) * (1.f + qlty - pyc);
        int ix_lt = (int)qltx, iy_lt = (int)qlty, ix_rb = (int)qrbx, iy_rb = (int)qrby;
        pi3[e * 3 + 0] = (ix_lt * 130 + iy_lt) * 64;
        pi3[e * 3 + 1] = (ix_rb * 130 + iy_rb) * 64;
        pi3[e * 3 + 2] = (iy_rb - iy_lt) * 64;
        pg4[e] = make_float4(glt * mv, grb * mv, glb * mv, grt * mv);
    }
    __syncthreads();

    // phase 2: gather+blend, a_lds[pos][k' = n*64 + ci] in f16 (proven pattern)
    {
        const float* xb = x_t + (size_t)b * 130 * 130 * 64;
        int ci = tid & 63;
        for (int it = 0; it < 36; ++it) {
            int point = (tid >> 6) + it * 4;
            int pos = (point * 456) >> 12;          // point/9, exact for point<288
            int n = point - pos * 9;
            int lt = pi3[point * 3 + 0];
            int rb = pi3[point * 3 + 1];
            int dy = pi3[point * 3 + 2];
            float4 g = pg4[point];
            float v = g.x * xb[lt + ci] + g.y * xb[rb + ci] +
                      g.z * xb[lt + dy + ci] + g.w * xb[rb - dy + ci];
            a_lds[pos * AHSTRIDE + n * 64 + ci] = (_Float16)v;
        }
    }
    __syncthreads();

    // phase 3: f16 dot2 (R16-proven). lane = co (+64), wave pg = pos group of 4.
    int lane = tid & 63, pg = tid >> 6;
    const uint4* W4 = (const uint4*)Wh;              // [(k8*128 + co)] = 8 f16
    float acc0[4] = {0.f, 0.f, 0.f, 0.f};
    float acc1[4] = {0.f, 0.f, 0.f, 0.f};

    uint4 wc0 = W4[lane];
    uint4 wc1 = W4[lane + 64];
    #pragma unroll 2
    for (int k8 = 0; k8 < 72; ++k8) {
        // prefetch next (k8=71 over-reads into Wh27 slot: benign)
        uint4 wn0 = W4[(k8 + 1) * 128 + lane];
        uint4 wn1 = W4[(k8 + 1) * 128 + lane + 64];
        #pragma unroll
        for (int p = 0; p < 4; ++p) {
            uint4 a = *(const uint4*)&a_lds[(pg * 4 + p) * AHSTRIDE + k8 * 8];  // broadcast
            acc0[p] = dot8(a, wc0, acc0[p]);
            acc1[p] = dot8(a, wc1, acc1[p]);
        }
        wc0 = wn0; wc1 = wn1;
    }
    __syncthreads();   // all a_lds reads done before aliasing overwrite

    // epilogue: stage via LDS, then coalesced global stores (proven path)
    float* outst = (float*)a_lds;                    // [128 co][17]
    #pragma unroll
    for (int p = 0; p < 4; ++p) {
        outst[lane * 17 + pg * 4 + p]        = acc0[p];
        outst[(lane + 64) * 17 + pg * 4 + p] = acc1[p];
    }
    __syncthreads();
    for (int e = tid; e < 2048; e += 256) {
        int co2 = e >> 4, wl = e & 15;
        out[((size_t)(b * 128 + co2) * 16384) + h * 128 + w0 + wl] = outst[co2 * 17 + wl];
    }
}

// ---------------- BN stats: one block per (b, co) ----------------
__global__ __launch_bounds__(256) void k_stats(
    const float* __restrict__ out, float* __restrict__ partial) {
    __shared__ float s1[256], s2[256];
    int blk = blockIdx.x;
    const float4* p = (const float4*)(out + (size_t)blk * 16384);
    float a1 = 0.f, a2 = 0.f;
    for (int i = threadIdx.x; i < 4096; i += 256) {
        float4 v = p[i];
        a1 += v.x + v.y + v.z + v.w;
        a2 += v.x * v.x + v.y * v.y + v.z * v.z + v.w * v.w;
    }
    s1[threadIdx.x] = a1; s2[threadIdx.x] = a2;
    __syncthreads();
    for (int s = 128; s > 0; s >>= 1) {
        if (threadIdx.x < (unsigned)s) {
            s1[threadIdx.x] += s1[threadIdx.x + s];
            s2[threadIdx.x] += s2[threadIdx.x + s];
        }
        __syncthreads();
    }
    if (threadIdx.x == 0) { partial[blk] = s1[0]; partial[1024 + blk] = s2[0]; }
}

// ---------------- fused finalize + BN + ReLU ----------------
__global__ void k_bnrelu(float* __restrict__ out, const float* __restrict__ partial,
                         const float* __restrict__ gamma, const float* __restrict__ beta) {
    int i = blockIdx.x * 256 + threadIdx.x;        // float4 index
    int c = (i >> 12) & 127;
    float s1 = 0.f, s2 = 0.f;
    #pragma unroll
    for (int b = 0; b < 8; ++b) {
        s1 += partial[b * 128 + c];
        s2 += partial[1024 + b * 128 + c];
    }
    const float M = 131072.f;
    float mean = s1 / M;
    float var = fmaxf(s2 / M - mean * mean, 0.f);
    float sc = gamma[c] * rsqrtf(var + 1e-5f);
    float bi = beta[c] - mean * sc;
    float4 v = ((float4*)out)[i];
    v.x = fmaxf(v.x * sc + bi, 0.f);
    v.y = fmaxf(v.y * sc + bi, 0.f);
    v.z = fmaxf(v.z * sc + bi, 0.f);
    v.w = fmaxf(v.w * sc + bi, 0.f);
    ((float4*)out)[i] = v;
}

extern "C" void kernel_launch(void* const* d_in, const int* in_sizes, int n_in,
                              void* d_out, int out_size, void* d_ws, size_t ws_size,
                              hipStream_t stream) {
    const float* x     = (const float*)d_in[0];
    const float* Wp    = (const float*)d_in[1];
    const float* bp    = (const float*)d_in[2];
    const float* Wm    = (const float*)d_in[3];
    const float* bm    = (const float*)d_in[4];
    const float* Wc    = (const float*)d_in[5];
    const float* gamma = (const float*)d_in[6];
    const float* beta  = (const float*)d_in[7];
    float* out = (float*)d_out;
    float* ws  = (float*)d_ws;

    // ws layout (floats)
    float* x_t      = ws;                                   // 8,652,800
    _Float16* Wh    = (_Float16*)(x_t + 8652800);           // 73,728 f16 (36,864 f)
    _Float16* Wh27  = (_Float16*)(x_t + 8652800 + 36864);   // 18,688 f16 (slot 36,864 f)
    float* offs     = x_t + 8652800 + 73728;                // 2,359,296
    float* mask     = offs + 2359296;                       // 1,179,648
    float* partial  = mask + 1179648;                       // 2048

    k_zero_border<<<258, 256, 0, stream>>>((float4*)x_t);
    k_pad_transpose<<<1024, 256, 0, stream>>>(x, x_t);
    k_wcomb<<<361, 256, 0, stream>>>(Wc, Wp, Wm, Wh, Wh27);
    k_offmask<<<4096, 256, 0, stream>>>(x_t, Wh27, bp, bm, offs, mask);
    k_main<<<8192, 256, 0, stream>>>(x_t, offs, mask, Wh, out);
    k_stats<<<1024, 256, 0, stream>>>(out, partial);
    k_bnrelu<<<16384, 256, 0, stream>>>(out, partial, gamma, beta);
}

// Round 20
// 353.782 us; speedup vs baseline: 1.2421x; 1.0277x over previous
//
#include <hip/hip_runtime.h>
#include <math.h>

// Problem constants: B=8, Cin=64, Cout=128, H=W=128, KS=3, N=9, K=576
#define KDIM 576
#define AHSTRIDE 584   // f16 per position row (576 + 8 pad), 1168 B = 73 uint4, 16B-aligned

typedef _Float16 h2 __attribute__((ext_vector_type(2)));

__device__ inline float dot8(uint4 a, uint4 w, float acc) {
    acc = __builtin_amdgcn_fdot2(__builtin_bit_cast(h2, a.x), __builtin_bit_cast(h2, w.x), acc, false);
    acc = __builtin_amdgcn_fdot2(__builtin_bit_cast(h2, a.y), __builtin_bit_cast(h2, w.y), acc, false);
    acc = __builtin_amdgcn_fdot2(__builtin_bit_cast(h2, a.z), __builtin_bit_cast(h2, w.z), acc, false);
    acc = __builtin_amdgcn_fdot2(__builtin_bit_cast(h2, a.w), __builtin_bit_cast(h2, w.w), acc, false);
    return acc;
}

// ---------------- zero padding border of x_t + the stats accumulator ----------------
__global__ void k_zero_border(float4* __restrict__ xt4, float4* __restrict__ partial4) {
    int i = blockIdx.x * 256 + threadIdx.x;        // 8*516*16 = 66048 border + 512 partial
    if (i >= 66560) return;
    if (i >= 66048) {
        partial4[i - 66048] = make_float4(0.f, 0.f, 0.f, 0.f);
        return;
    }
    int f4 = i & 15, cell = (i >> 4) % 516, b = i / (516 * 16);
    int r, c;
    if (cell < 130)      { r = 0;              c = cell; }
    else if (cell < 260) { r = 129;            c = cell - 130; }
    else if (cell < 388) { r = cell - 260 + 1; c = 0; }
    else                 { r = cell - 388 + 1; c = 129; }
    xt4[(((size_t)b * 130 + r) * 130 + c) * 16 + f4] = make_float4(0.f, 0.f, 0.f, 0.f);
}

// ---------------- pad + NCHW->NHWC transpose ----------------
__global__ __launch_bounds__(256) void k_pad_transpose(
    const float* __restrict__ x, float* __restrict__ x_t) {
    __shared__ float lds[128 * 65];
    int b = blockIdx.x >> 7;
    int h = blockIdx.x & 127;
    for (int e = threadIdx.x; e < 64 * 128; e += 256) {
        int ci = e >> 7, w = e & 127;
        lds[w * 65 + ci] = x[((b * 64 + ci) * 128 + h) * 128 + w];
    }
    __syncthreads();
    for (int e = threadIdx.x; e < 128 * 64; e += 256) {
        int w = e >> 6, ci = e & 63;
        x_t[((b * 130 + h + 1) * 130 + (w + 1)) * 64 + ci] = lds[w * 65 + ci];
    }
}

// ---------------- combined weight prepack: Wc -> Wh (k8-blocked), Wp/Wm -> Wh27 ----------------
__global__ void k_wcomb(const float* __restrict__ Wc, const float* __restrict__ Wp,
                        const float* __restrict__ Wm, _Float16* __restrict__ Wh,
                        _Float16* __restrict__ Wh27) {
    int gb = blockIdx.x;
    if (gb < 288) {
        int e = gb * 256 + threadIdx.x;
        if (e >= 72 * 128 * 8) return;
        int j = e & 7, idx = e >> 3;
        int co = idx & 127, k8 = idx >> 7;
        int kp = k8 * 8 + j;
        int n = kp >> 6, ci = kp & 63;
        Wh[e] = (_Float16)Wc[co * KDIM + ci * 9 + n];
    } else {
        int e = (gb - 288) * 256 + threadIdx.x;
        if (e >= 73 * 32 * 8) return;
        int j = e & 7, idx = e >> 3;
        int co = idx & 31, k8 = idx >> 5;
        float v = 0.f;
        if (k8 < 72 && co < 27) {
            int kp = k8 * 8 + j;
            int n = kp >> 6, ci = kp & 63;
            v = (co < 18) ? Wp[co * KDIM + ci * 9 + n] : Wm[(co - 18) * KDIM + ci * 9 + n];
        }
        Wh27[e] = (_Float16)v;
    }
}

// ---------------- offset + mask convs: f16 fdot2 (R17-proven) ----------------
__global__ __launch_bounds__(256) void k_offmask(
    const float* __restrict__ x_t, const _Float16* __restrict__ Wh27,
    const float* __restrict__ bp, const float* __restrict__ bm,
    float* __restrict__ offs, float* __restrict__ mask) {
    __shared__ __align__(16) _Float16 a_lds[32 * AHSTRIDE];   // 37376 B

    int blk = blockIdx.x;
    int b  = blk & 7;
    int rem = blk >> 3;
    int h  = rem >> 2;
    int w0 = (rem & 3) * 32;
    int tid = threadIdx.x;

    {
        const float* xb = x_t + (size_t)b * 130 * 130 * 64;
        int ci = tid & 63;
        for (int it = 0; it < 72; ++it) {
            int point = (tid >> 6) + it * 4;            // pos*9 + n, point < 288
            int pos = (point * 456) >> 12;
            int n = point - pos * 9;
            int kx = n / 3, ky = n - kx * 3;
            float v = xb[((h + kx) * 130 + (w0 + pos + ky)) * 64 + ci];
            a_lds[pos * AHSTRIDE + n * 64 + ci] = (_Float16)v;
        }
    }
    __syncthreads();

    int co = tid & 31;
    int ph = (tid >> 5) & 1;
    int wv = tid >> 6;
    int pbase = wv * 8 + ph * 4;
    const uint4* W4 = (const uint4*)Wh27;
    float acc[4] = {0.f, 0.f, 0.f, 0.f};
    uint4 wc = W4[co];
    for (int k8 = 0; k8 < 72; ++k8) {
        uint4 wn = W4[(k8 + 1) * 32 + co];              // k8=71 reads zero pad row
        #pragma unroll
        for (int p = 0; p < 4; ++p) {
            uint4 a = *(const uint4*)&a_lds[(pbase + p) * AHSTRIDE + k8 * 8];
            acc[p] = dot8(a, wc, acc[p]);
        }
        wc = wn;
    }

    if (co < 27) {
        #pragma unroll
        for (int p = 0; p < 4; ++p) {
            int w = w0 + pbase + p;
            int idx = ((b * 128 + h) * 128 + w);
            if (co < 18) {
                offs[idx * 18 + co] = acc[p] + bp[co];
            } else {
                float v = acc[p] + bm[co - 18];
                mask[idx * 9 + (co - 18)] = 1.f / (1.f + __expf(-v));
            }
        }
    }
}

// ---------------- main: deformable sample -> f16 fdot2 dot + fused BN partial stats ----------------
// block = 16 positions; grid = 8192, XCD-pinned; LDS 22.7 KB -> 7 blocks/CU.
// Phase 3 (R16-proven): wave = pos-group of 4 (broadcast ds_reads), lane = co (+64);
// thread = 2 co x 4 pos. Epilogue also computes per-(b,co) partial sums -> atomicAdd.
__global__ __launch_bounds__(256, 7) void k_main(
    const float* __restrict__ x_t, const float* __restrict__ offs,
    const float* __restrict__ mask, const _Float16* __restrict__ Wh,
    float* __restrict__ out, float* __restrict__ partial) {
    __shared__ __align__(16) _Float16 a_lds[16 * AHSTRIDE];   // 18688 B; reused as outst
    __shared__ int    pi3[144 * 3];                           // lt, rb, dy
    __shared__ float4 pg4[144];

    int blk = blockIdx.x;
    int b  = blk & 7;                  // XCD swizzle: one batch per XCD
    int rem = blk >> 3;
    int h  = rem >> 3;
    int w0 = (rem & 7) * 16;
    int tid = threadIdx.x;

    // phase 1: sampling coords for 16 pos x 9 pts (proven math)
    if (tid < 144) {
        int e = tid;
        int pos = e / 9, n = e - pos * 9;
        int w = w0 + pos;
        int idx = ((b * 128 + h) * 128 + w);
        float ox = offs[idx * 18 + n];
        float oy = offs[idx * 18 + 9 + n];
        float mv = mask[idx * 9 + n];
        float px = ox + (float)(h + n / 3);
        float py = oy + (float)(w + n % 3);
        float flx = floorf(px), fly = floorf(py);
        float qltx = fminf(fmaxf(flx, 0.f), 129.f);
        float qlty = fminf(fmaxf(fly, 0.f), 129.f);
        float qrbx = fminf(fmaxf(flx + 1.f, 0.f), 129.f);
        float qrby = fminf(fmaxf(fly + 1.f, 0.f), 129.f);
        float pxc = fminf(fmaxf(px, 0.f), 129.f);
        float pyc = fminf(fmaxf(py, 0.f), 129.f);
        float glt = (1.f + qltx - pxc) * (1.f + qlty - pyc);
        float grb = (1.f - qrbx + pxc) * (1.f - qrby + pyc);
        float glb = (1.f + qltx - pxc) * (1.f - qrby + pyc);
        float grt = (1.f - qrbx + pxc) * (1.f + qlty - pyc);
        int ix_lt = (int)qltx, iy_lt = (int)qlty, ix_rb = (int)qrbx, iy_rb = (int)qrby;
        pi3[e * 3 + 0] = (ix_lt * 130 + iy_lt) * 64;
        pi3[e * 3 + 1] = (ix_rb * 130 + iy_rb) * 64;
        pi3[e * 3 + 2] = (iy_rb - iy_lt) * 64;
        pg4[e] = make_float4(glt * mv, grb * mv, glb * mv, grt * mv);
    }
    __syncthreads();

    // phase 2: gather+blend, a_lds[pos][k' = n*64 + ci] in f16 (proven pattern)
    {
        const float* xb = x_t + (size_t)b * 130 * 130 * 64;
        int ci = tid & 63;
        for (int it = 0; it < 36; ++it) {
            int point = (tid >> 6) + it * 4;
            int pos = (point * 456) >> 12;          // point/9, exact for point<288
            int n = point - pos * 9;
            int lt = pi3[point * 3 + 0];
            int rb = pi3[point * 3 + 1];
            int dy = pi3[point * 3 + 2];
            float4 g = pg4[point];
            float v = g.x * xb[lt + ci] + g.y * xb[rb + ci] +
                      g.z * xb[lt + dy + ci] + g.w * xb[rb - dy + ci];
            a_lds[pos * AHSTRIDE + n * 64 + ci] = (_Float16)v;
        }
    }
    __syncthreads();

    // phase 3: f16 dot2 (R16-proven). lane = co (+64), wave pg = pos group of 4.
    int lane = tid & 63, pg = tid >> 6;
    const uint4* W4 = (const uint4*)Wh;              // [(k8*128 + co)] = 8 f16
    float acc0[4] = {0.f, 0.f, 0.f, 0.f};
    float acc1[4] = {0.f, 0.f, 0.f, 0.f};

    uint4 wc0 = W4[lane];
    uint4 wc1 = W4[lane + 64];
    #pragma unroll 2
    for (int k8 = 0; k8 < 72; ++k8) {
        // prefetch next (k8=71 over-reads into Wh27 slot: benign)
        uint4 wn0 = W4[(k8 + 1) * 128 + lane];
        uint4 wn1 = W4[(k8 + 1) * 128 + lane + 64];
        #pragma unroll
        for (int p = 0; p < 4; ++p) {
            uint4 a = *(const uint4*)&a_lds[(pg * 4 + p) * AHSTRIDE + k8 * 8];  // broadcast
            acc0[p] = dot8(a, wc0, acc0[p]);
            acc1[p] = dot8(a, wc1, acc1[p]);
        }
        wc0 = wn0; wc1 = wn1;
    }
    __syncthreads();   // all a_lds reads done before aliasing overwrite

    // epilogue: stage via LDS, fused BN partial stats, coalesced global stores
    float* outst = (float*)a_lds;                    // [128 co][17]
    #pragma unroll
    for (int p = 0; p < 4; ++p) {
        outst[lane * 17 + pg * 4 + p]        = acc0[p];
        outst[(lane + 64) * 17 + pg * 4 + p] = acc1[p];
    }
    __syncthreads();
    if (tid < 128) {                                 // per-co partials over this block's 16 w
        float s1 = 0.f, s2 = 0.f;
        #pragma unroll
        for (int p = 0; p < 16; ++p) {
            float v = outst[tid * 17 + p];
            s1 += v; s2 += v * v;
        }
        atomicAdd(&partial[b * 128 + tid], s1);
        atomicAdd(&partial[1024 + b * 128 + tid], s2);
    }
    for (int e = tid; e < 2048; e += 256) {
        int co2 = e >> 4, wl = e & 15;
        out[((size_t)(b * 128 + co2) * 16384) + h * 128 + w0 + wl] = outst[co2 * 17 + wl];
    }
}

// ---------------- fused finalize + BN + ReLU ----------------
__global__ void k_bnrelu(float* __restrict__ out, const float* __restrict__ partial,
                         const float* __restrict__ gamma, const float* __restrict__ beta) {
    int i = blockIdx.x * 256 + threadIdx.x;        // float4 index
    int c = (i >> 12) & 127;
    float s1 = 0.f, s2 = 0.f;
    #pragma unroll
    for (int b = 0; b < 8; ++b) {
        s1 += partial[b * 128 + c];
        s2 += partial[1024 + b * 128 + c];
    }
    const float M = 131072.f;
    float mean = s1 / M;
    float var = fmaxf(s2 / M - mean * mean, 0.f);
    float sc = gamma[c] * rsqrtf(var + 1e-5f);
    float bi = beta[c] - mean * sc;
    float4 v = ((float4*)out)[i];
    v.x = fmaxf(v.x * sc + bi, 0.f);
    v.y = fmaxf(v.y * sc + bi, 0.f);
    v.z = fmaxf(v.z * sc + bi, 0.f);
    v.w = fmaxf(v.w * sc + bi, 0.f);
    ((float4*)out)[i] = v;
}

extern "C" void kernel_launch(void* const* d_in, const int* in_sizes, int n_in,
                              void* d_out, int out_size, void* d_ws, size_t ws_size,
                              hipStream_t stream) {
    const float* x     = (const float*)d_in[0];
    const float* Wp    = (const float*)d_in[1];
    const float* bp    = (const float*)d_in[2];
    const float* Wm    = (const float*)d_in[3];
    const float* bm    = (const float*)d_in[4];
    const float* Wc    = (const float*)d_in[5];
    const float* gamma = (const float*)d_in[6];
    const float* beta  = (const float*)d_in[7];
    float* out = (float*)d_out;
    float* ws  = (float*)d_ws;

    // ws layout (floats)
    float* x_t      = ws;                                   // 8,652,800
    _Float16* Wh    = (_Float16*)(x_t + 8652800);           // 73,728 f16 (36,864 f)
    _Float16* Wh27  = (_Float16*)(x_t + 8652800 + 36864);   // 18,688 f16 (slot 36,864 f)
    float* offs     = x_t + 8652800 + 73728;                // 2,359,296
    float* mask     = offs + 2359296;                       // 1,179,648
    float* partial  = mask + 1179648;                       // 2048

    k_zero_border<<<260, 256, 0, stream>>>((float4*)x_t, (float4*)partial);
    k_pad_transpose<<<1024, 256, 0, stream>>>(x, x_t);
    k_wcomb<<<361, 256, 0, stream>>>(Wc, Wp, Wm, Wh, Wh27);
    k_offmask<<<4096, 256, 0, stream>>>(x_t, Wh27, bp, bm, offs, mask);
    k_main<<<8192, 256, 0, stream>>>(x_t, offs, mask, Wh, out, partial);
    k_bnrelu<<<16384, 256, 0, stream>>>(out, partial, gamma, beta);
}

// Round 21
// 351.344 us; speedup vs baseline: 1.2507x; 1.0069x over previous
//
#include <hip/hip_runtime.h>
#include <math.h>

// Problem constants: B=8, Cin=64, Cout=128, H=W=128, KS=3, N=9, K=576
#define KDIM 576
#define AHSTRIDE 584   // f16 per position row (576 + 8 pad), 1168 B = 73 uint4, 16B-aligned

typedef _Float16 h2 __attribute__((ext_vector_type(2)));

__device__ inline float dot8(uint4 a, uint4 w, float acc) {
    acc = __builtin_amdgcn_fdot2(__builtin_bit_cast(h2, a.x), __builtin_bit_cast(h2, w.x), acc, false);
    acc = __builtin_amdgcn_fdot2(__builtin_bit_cast(h2, a.y), __builtin_bit_cast(h2, w.y), acc, false);
    acc = __builtin_amdgcn_fdot2(__builtin_bit_cast(h2, a.z), __builtin_bit_cast(h2, w.z), acc, false);
    acc = __builtin_amdgcn_fdot2(__builtin_bit_cast(h2, a.w), __builtin_bit_cast(h2, w.w), acc, false);
    return acc;
}

// ---------------- zero padding border of x_t (f16) + the stats accumulator ----------------
// border cells per b: 516; each cell = 64 f16 = 128 B = 8 uint4. 8*516*8 = 33024 + 512 partial
__global__ void k_zero_border(uint4* __restrict__ xt4, float4* __restrict__ partial4) {
    int i = blockIdx.x * 256 + threadIdx.x;
    if (i >= 33536) return;
    if (i >= 33024) {
        partial4[i - 33024] = make_float4(0.f, 0.f, 0.f, 0.f);
        return;
    }
    int f4 = i & 7, cell = (i >> 3) % 516, b = i / (516 * 8);
    int r, c;
    if (cell < 130)      { r = 0;              c = cell; }
    else if (cell < 260) { r = 129;            c = cell - 130; }
    else if (cell < 388) { r = cell - 260 + 1; c = 0; }
    else                 { r = cell - 388 + 1; c = 129; }
    xt4[(((size_t)b * 130 + r) * 130 + c) * 8 + f4] = make_uint4(0u, 0u, 0u, 0u);
}

// ---------------- pad + NCHW->NHWC transpose, f32 -> f16 ----------------
__global__ __launch_bounds__(256) void k_pad_transpose(
    const float* __restrict__ x, _Float16* __restrict__ x_t) {
    __shared__ float lds[128 * 65];
    int b = blockIdx.x >> 7;
    int h = blockIdx.x & 127;
    for (int e = threadIdx.x; e < 64 * 128; e += 256) {
        int ci = e >> 7, w = e & 127;
        lds[w * 65 + ci] = x[((b * 64 + ci) * 128 + h) * 128 + w];
    }
    __syncthreads();
    for (int e = threadIdx.x; e < 128 * 64; e += 256) {
        int w = e >> 6, ci = e & 63;
        x_t[((b * 130 + h + 1) * 130 + (w + 1)) * 64 + ci] = (_Float16)lds[w * 65 + ci];
    }
}

// ---------------- combined weight prepack: Wc -> Wh (k8-blocked), Wp/Wm -> Wh27 ----------------
__global__ void k_wcomb(const float* __restrict__ Wc, const float* __restrict__ Wp,
                        const float* __restrict__ Wm, _Float16* __restrict__ Wh,
                        _Float16* __restrict__ Wh27) {
    int gb = blockIdx.x;
    if (gb < 288) {
        int e = gb * 256 + threadIdx.x;
        if (e >= 72 * 128 * 8) return;
        int j = e & 7, idx = e >> 3;
        int co = idx & 127, k8 = idx >> 7;
        int kp = k8 * 8 + j;
        int n = kp >> 6, ci = kp & 63;
        Wh[e] = (_Float16)Wc[co * KDIM + ci * 9 + n];
    } else {
        int e = (gb - 288) * 256 + threadIdx.x;
        if (e >= 73 * 32 * 8) return;
        int j = e & 7, idx = e >> 3;
        int co = idx & 31, k8 = idx >> 5;
        float v = 0.f;
        if (k8 < 72 && co < 27) {
            int kp = k8 * 8 + j;
            int n = kp >> 6, ci = kp & 63;
            v = (co < 18) ? Wp[co * KDIM + ci * 9 + n] : Wm[(co - 18) * KDIM + ci * 9 + n];
        }
        Wh27[e] = (_Float16)v;
    }
}

// ---------------- offset + mask convs: f16 fdot2 (R17-proven; staging now pure f16 copy) ----------------
__global__ __launch_bounds__(256) void k_offmask(
    const _Float16* __restrict__ x_t, const _Float16* __restrict__ Wh27,
    const float* __restrict__ bp, const float* __restrict__ bm,
    float* __restrict__ offs, float* __restrict__ mask) {
    __shared__ __align__(16) _Float16 a_lds[32 * AHSTRIDE];   // 37376 B

    int blk = blockIdx.x;
    int b  = blk & 7;
    int rem = blk >> 3;
    int h  = rem >> 2;
    int w0 = (rem & 3) * 32;
    int tid = threadIdx.x;

    {
        const _Float16* xb = x_t + (size_t)b * 130 * 130 * 64;
        int ci = tid & 63;
        for (int it = 0; it < 72; ++it) {
            int point = (tid >> 6) + it * 4;            // pos*9 + n, point < 288
            int pos = (point * 456) >> 12;
            int n = point - pos * 9;
            int kx = n / 3, ky = n - kx * 3;
            a_lds[pos * AHSTRIDE + n * 64 + ci] =
                xb[((h + kx) * 130 + (w0 + pos + ky)) * 64 + ci];
        }
    }
    __syncthreads();

    int co = tid & 31;
    int ph = (tid >> 5) & 1;
    int wv = tid >> 6;
    int pbase = wv * 8 + ph * 4;
    const uint4* W4 = (const uint4*)Wh27;
    float acc[4] = {0.f, 0.f, 0.f, 0.f};
    uint4 wc = W4[co];
    for (int k8 = 0; k8 < 72; ++k8) {
        uint4 wn = W4[(k8 + 1) * 32 + co];              // k8=71 reads zero pad row
        #pragma unroll
        for (int p = 0; p < 4; ++p) {
            uint4 a = *(const uint4*)&a_lds[(pbase + p) * AHSTRIDE + k8 * 8];
            acc[p] = dot8(a, wc, acc[p]);
        }
        wc = wn;
    }

    if (co < 27) {
        #pragma unroll
        for (int p = 0; p < 4; ++p) {
            int w = w0 + pbase + p;
            int idx = ((b * 128 + h) * 128 + w);
            if (co < 18) {
                offs[idx * 18 + co] = acc[p] + bp[co];
            } else {
                float v = acc[p] + bm[co - 18];
                mask[idx * 9 + (co - 18)] = 1.f / (1.f + __expf(-v));
            }
        }
    }
}

// ---------------- main: deformable sample (f16 gathers) -> f16 fdot2 dot + fused stats ----------------
// block = 16 positions; grid = 8192, XCD-pinned; per-batch x_t slab now 2.16 MB -> L2-resident.
__global__ __launch_bounds__(256, 7) void k_main(
    const _Float16* __restrict__ x_t, const float* __restrict__ offs,
    const float* __restrict__ mask, const _Float16* __restrict__ Wh,
    float* __restrict__ out, float* __restrict__ partial) {
    __shared__ __align__(16) _Float16 a_lds[16 * AHSTRIDE];   // 18688 B; reused as outst
    __shared__ int    pi3[144 * 3];                           // lt, rb, dy
    __shared__ float4 pg4[144];

    int blk = blockIdx.x;
    int b  = blk & 7;                  // XCD swizzle: one batch per XCD
    int rem = blk >> 3;
    int h  = rem >> 3;
    int w0 = (rem & 7) * 16;
    int tid = threadIdx.x;

    // phase 1: sampling coords for 16 pos x 9 pts (proven math)
    if (tid < 144) {
        int e = tid;
        int pos = e / 9, n = e - pos * 9;
        int w = w0 + pos;
        int idx = ((b * 128 + h) * 128 + w);
        float ox = offs[idx * 18 + n];
        float oy = offs[idx * 18 + 9 + n];
        float mv = mask[idx * 9 + n];
        float px = ox + (float)(h + n / 3);
        float py = oy + (float)(w + n % 3);
        float flx = floorf(px), fly = floorf(py);
        float qltx = fminf(fmaxf(flx, 0.f), 129.f);
        float qlty = fminf(fmaxf(fly, 0.f), 129.f);
        float qrbx = fminf(fmaxf(flx + 1.f, 0.f), 129.f);
        float qrby = fminf(fmaxf(fly + 1.f, 0.f), 129.f);
        float pxc = fminf(fmaxf(px, 0.f), 129.f);
        float pyc = fminf(fmaxf(py, 0.f), 129.f);
        float glt = (1.f + qltx - pxc) * (1.f + qlty - pyc);
        float grb = (1.f - qrbx + pxc) * (1.f - qrby + pyc);
        float glb = (1.f + qltx - pxc) * (1.f - qrby + pyc);
        float grt = (1.f - qrbx + pxc) * (1.f + qlty - pyc);
        int ix_lt = (int)qltx, iy_lt = (int)qlty, ix_rb = (int)qrbx, iy_rb = (int)qrby;
        pi3[e * 3 + 0] = (ix_lt * 130 + iy_lt) * 64;
        pi3[e * 3 + 1] = (ix_rb * 130 + iy_rb) * 64;
        pi3[e * 3 + 2] = (iy_rb - iy_lt) * 64;
        pg4[e] = make_float4(glt * mv, grb * mv, glb * mv, grt * mv);
    }
    __syncthreads();

    // phase 2: gather+blend from f16 x_t (L2-resident), fp32 blend, f16 store
    {
        const _Float16* xb = x_t + (size_t)b * 130 * 130 * 64;
        int ci = tid & 63;
        for (int it = 0; it < 36; ++it) {
            int point = (tid >> 6) + it * 4;
            int pos = (point * 456) >> 12;          // point/9, exact for point<288
            int n = point - pos * 9;
            int lt = pi3[point * 3 + 0];
            int rb = pi3[point * 3 + 1];
            int dy = pi3[point * 3 + 2];
            float4 g = pg4[point];
            float v = g.x * (float)xb[lt + ci] + g.y * (float)xb[rb + ci] +
                      g.z * (float)xb[lt + dy + ci] + g.w * (float)xb[rb - dy + ci];
            a_lds[pos * AHSTRIDE + n * 64 + ci] = (_Float16)v;
        }
    }
    __syncthreads();

    // phase 3: f16 dot2 (R16-proven). lane = co (+64), wave pg = pos group of 4.
    int lane = tid & 63, pg = tid >> 6;
    const uint4* W4 = (const uint4*)Wh;              // [(k8*128 + co)] = 8 f16
    float acc0[4] = {0.f, 0.f, 0.f, 0.f};
    float acc1[4] = {0.f, 0.f, 0.f, 0.f};

    uint4 wc0 = W4[lane];
    uint4 wc1 = W4[lane + 64];
    #pragma unroll 2
    for (int k8 = 0; k8 < 72; ++k8) {
        // prefetch next (k8=71 over-reads into Wh27 slot: benign)
        uint4 wn0 = W4[(k8 + 1) * 128 + lane];
        uint4 wn1 = W4[(k8 + 1) * 128 + lane + 64];
        #pragma unroll
        for (int p = 0; p < 4; ++p) {
            uint4 a = *(const uint4*)&a_lds[(pg * 4 + p) * AHSTRIDE + k8 * 8];  // broadcast
            acc0[p] = dot8(a, wc0, acc0[p]);
            acc1[p] = dot8(a, wc1, acc1[p]);
        }
        wc0 = wn0; wc1 = wn1;
    }
    __syncthreads();   // all a_lds reads done before aliasing overwrite

    // epilogue: stage via LDS, fused BN partial stats, coalesced global stores
    float* outst = (float*)a_lds;                    // [128 co][17]
    #pragma unroll
    for (int p = 0; p < 4; ++p) {
        outst[lane * 17 + pg * 4 + p]        = acc0[p];
        outst[(lane + 64) * 17 + pg * 4 + p] = acc1[p];
    }
    __syncthreads();
    if (tid < 128) {                                 // per-co partials over this block's 16 w
        float s1 = 0.f, s2 = 0.f;
        #pragma unroll
        for (int p = 0; p < 16; ++p) {
            float v = outst[tid * 17 + p];
            s1 += v; s2 += v * v;
        }
        atomicAdd(&partial[b * 128 + tid], s1);
        atomicAdd(&partial[1024 + b * 128 + tid], s2);
    }
    for (int e = tid; e < 2048; e += 256) {
        int co2 = e >> 4, wl = e & 15;
        out[((size_t)(b * 128 + co2) * 16384) + h * 128 + w0 + wl] = outst[co2 * 17 + wl];
    }
}

// ---------------- fused finalize + BN + ReLU ----------------
__global__ void k_bnrelu(float* __restrict__ out, const float* __restrict__ partial,
                         const float* __restrict__ gamma, const float* __restrict__ beta) {
    int i = blockIdx.x * 256 + threadIdx.x;        // float4 index
    int c = (i >> 12) & 127;
    float s1 = 0.f, s2 = 0.f;
    #pragma unroll
    for (int b = 0; b < 8; ++b) {
        s1 += partial[b * 128 + c];
        s2 += partial[1024 + b * 128 + c];
    }
    const float M = 131072.f;
    float mean = s1 / M;
    float var = fmaxf(s2 / M - mean * mean, 0.f);
    float sc = gamma[c] * rsqrtf(var + 1e-5f);
    float bi = beta[c] - mean * sc;
    float4 v = ((float4*)out)[i];
    v.x = fmaxf(v.x * sc + bi, 0.f);
    v.y = fmaxf(v.y * sc + bi, 0.f);
    v.z = fmaxf(v.z * sc + bi, 0.f);
    v.w = fmaxf(v.w * sc + bi, 0.f);
    ((float4*)out)[i] = v;
}

extern "C" void kernel_launch(void* const* d_in, const int* in_sizes, int n_in,
                              void* d_out, int out_size, void* d_ws, size_t ws_size,
                              hipStream_t stream) {
    const float* x     = (const float*)d_in[0];
    const float* Wp    = (const float*)d_in[1];
    const float* bp    = (const float*)d_in[2];
    const float* Wm    = (const float*)d_in[3];
    const float* bm    = (const float*)d_in[4];
    const float* Wc    = (const float*)d_in[5];
    const float* gamma = (const float*)d_in[6];
    const float* beta  = (const float*)d_in[7];
    float* out = (float*)d_out;
    float* ws  = (float*)d_ws;

    // ws layout (floats); x_t is f16 and occupies 4,326,400 float-slots
    _Float16* x_t   = (_Float16*)ws;                        // 8,652,800 f16
    _Float16* Wh    = (_Float16*)(ws + 4326400);            // 73,728 f16 (36,864 f)
    _Float16* Wh27  = (_Float16*)(ws + 4326400 + 36864);    // 18,688 f16 (slot 36,864 f)
    float* offs     = ws + 4326400 + 73728;                 // 2,359,296
    float* mask     = offs + 2359296;                       // 1,179,648
    float* partial  = mask + 1179648;                       // 2048

    k_zero_border<<<131, 256, 0, stream>>>((uint4*)x_t, (float4*)partial);
    k_pad_transpose<<<1024, 256, 0, stream>>>(x, x_t);
    k_wcomb<<<361, 256, 0, stream>>>(Wc, Wp, Wm, Wh, Wh27);
    k_offmask<<<4096, 256, 0, stream>>>(x_t, Wh27, bp, bm, offs, mask);
    k_main<<<8192, 256, 0, stream>>>(x_t, offs, mask, Wh, out, partial);
    k_bnrelu<<<16384, 256, 0, stream>>>(out, partial, gamma, beta);
}